// Round 2
// baseline (499.676 us; speedup 1.0000x reference)
//
#include <hip/hip_runtime.h>
#include <hip/hip_bf16.h>

#define NBATCH 2048
#define SEQL   128
#define EMB    32
#define NCODE  10

// flat output offsets (f32 elements)
#define OFF_LOG  0
#define OFF_PUZ  33554432
#define OFF_FEAT 35397632
#define OFF_Q    153362432
#define OFF_LOSS 271327232

// LDS layout (byte offsets into sm[40960]) with phase liveness:
//  xs   [32][128] f32 @ 0      (P0-P1)
//  h1   [64][64]  f32 @ 16384  (P1-P2)
//  h2   [64][32]  f32 @ 32768  (P2-P3)
//  h3   [64][30]  f32 @ 0      (P3-P5)   over xs
//  cbs  [10][64]  f32 @ 7680   (P3-P5)
//  codes[30]      i32 @ 10240  (P4-P5)
//  encf [30][64]  f32 @ 10368  (P5-P6)   over h1
//  qf   [30][64]  f32 @ 18048  (P5-P6)
//  ft   [64][32]  f32 @ 25728  (P5-P6)   over h2 tail
//  g1   [64][32]  f32 @ 0      (P6-P7)   over h3/cbs
//  g2   [64][64]  f32 @ 8192   (P7-P8)   over codes/encf/qf head
//  dc   [32][128] f32 @ 24576  (P8-P9)   over qf tail/ft
//  ows  [32][129] f32 @ 0      (P9)      over g1/g2 head
//  obs  [128]     f32 @ 16512  (P9)

__global__ __launch_bounds__(256, 4)
void vae_fused(const int* __restrict__ tidx, const float* __restrict__ emb,
               const float* __restrict__ w1, const float* __restrict__ b1,
               const float* __restrict__ w2, const float* __restrict__ b2,
               const float* __restrict__ w3, const float* __restrict__ b3,
               const float* __restrict__ cb,
               const float* __restrict__ dw1, const float* __restrict__ db1,
               const float* __restrict__ dw2, const float* __restrict__ db2,
               const float* __restrict__ dw3, const float* __restrict__ db3,
               const float* __restrict__ ow, const float* __restrict__ ob,
               float* __restrict__ out, float* __restrict__ loss_part)
{
    __shared__ char sm[40960];
    float* xs   = (float*)(sm);
    float* h1   = (float*)(sm + 16384);
    float* h2   = (float*)(sm + 32768);
    float* h3   = (float*)(sm);
    float* cbs  = (float*)(sm + 7680);
    int*   codes= (int*)  (sm + 10240);
    float* encf = (float*)(sm + 10368);
    float* qf   = (float*)(sm + 18048);
    float* ft   = (float*)(sm + 25728);
    float* g1   = (float*)(sm);
    float* g2   = (float*)(sm + 8192);
    float* dc   = (float*)(sm + 24576);
    float* ows  = (float*)(sm);
    float* obs  = (float*)(sm + 16512);

    const int b   = blockIdx.x;
    const int tid = threadIdx.x;
    const int* ti = tidx + b * SEQL;

    // ---------- P0: embedding gather  xs[e][l] = emb[ti[l]][e] ----------
    for (int v = tid; v < EMB * SEQL; v += 256) {
        int e = v >> 7, l = v & 127;
        xs[v] = emb[ti[l] * EMB + e];
    }
    __syncthreads();

    // ---------- P1: conv1 32->64ch, L128->64, k3 s2 p1, relu ----------
    {
        const int o0 = (tid >> 4) * 4;
        const int t0 = (tid & 15) * 4;
        float acc[4][4];
        #pragma unroll
        for (int a = 0; a < 4; a++) {
            float bb = b1[o0 + a];
            #pragma unroll
            for (int c = 0; c < 4; c++) acc[a][c] = bb;
        }
        for (int i = 0; i < 32; i++) {
            #pragma unroll
            for (int kk = 0; kk < 3; kk++) {
                float wv[4], xv[4];
                #pragma unroll
                for (int a = 0; a < 4; a++) wv[a] = w1[((o0 + a) * 32 + i) * 3 + kk];
                #pragma unroll
                for (int c = 0; c < 4; c++) {
                    int l = 2 * (t0 + c) + kk - 1;
                    xv[c] = (l >= 0 && l < 128) ? xs[i * 128 + l] : 0.f;
                }
                #pragma unroll
                for (int a = 0; a < 4; a++)
                    #pragma unroll
                    for (int c = 0; c < 4; c++)
                        acc[a][c] = fmaf(wv[a], xv[c], acc[a][c]);
            }
        }
        #pragma unroll
        for (int a = 0; a < 4; a++)
            #pragma unroll
            for (int c = 0; c < 4; c++)
                h1[(o0 + a) * 64 + t0 + c] = fmaxf(acc[a][c], 0.f);
    }
    __syncthreads();

    // ---------- P2: conv2 64->64ch, 64->32, k3 s2 p1, relu ----------
    {
        const int o0 = (tid >> 3) * 2;
        const int t0 = (tid & 7) * 4;
        float acc[2][4];
        #pragma unroll
        for (int a = 0; a < 2; a++) {
            float bb = b2[o0 + a];
            #pragma unroll
            for (int c = 0; c < 4; c++) acc[a][c] = bb;
        }
        for (int i = 0; i < 64; i++) {
            #pragma unroll
            for (int kk = 0; kk < 3; kk++) {
                float wv[2], xv[4];
                #pragma unroll
                for (int a = 0; a < 2; a++) wv[a] = w2[((o0 + a) * 64 + i) * 3 + kk];
                #pragma unroll
                for (int c = 0; c < 4; c++) {
                    int l = 2 * (t0 + c) + kk - 1;
                    xv[c] = (l >= 0 && l < 64) ? h1[i * 64 + l] : 0.f;
                }
                #pragma unroll
                for (int a = 0; a < 2; a++)
                    #pragma unroll
                    for (int c = 0; c < 4; c++)
                        acc[a][c] = fmaf(wv[a], xv[c], acc[a][c]);
            }
        }
        #pragma unroll
        for (int a = 0; a < 2; a++)
            #pragma unroll
            for (int c = 0; c < 4; c++)
                h2[(o0 + a) * 32 + t0 + c] = fmaxf(acc[a][c], 0.f);
    }
    __syncthreads();

    // ---------- P3: conv3 64->64ch, 32->30, k3 s1 p0 (no relu); load codebook ----------
    {
        const int o0 = (tid >> 3) * 2;
        const int t0 = (tid & 7) * 4;
        float acc[2][4];
        #pragma unroll
        for (int a = 0; a < 2; a++) {
            float bb = b3[o0 + a];
            #pragma unroll
            for (int c = 0; c < 4; c++) acc[a][c] = bb;
        }
        for (int i = 0; i < 64; i++) {
            #pragma unroll
            for (int kk = 0; kk < 3; kk++) {
                float wv[2], xv[4];
                #pragma unroll
                for (int a = 0; a < 2; a++) wv[a] = w3[((o0 + a) * 64 + i) * 3 + kk];
                #pragma unroll
                for (int c = 0; c < 4; c++) {
                    int l = t0 + c + kk;
                    xv[c] = (l < 32) ? h2[i * 32 + l] : 0.f;
                }
                #pragma unroll
                for (int a = 0; a < 2; a++)
                    #pragma unroll
                    for (int c = 0; c < 4; c++)
                        acc[a][c] = fmaf(wv[a], xv[c], acc[a][c]);
            }
        }
        #pragma unroll
        for (int a = 0; a < 2; a++)
            #pragma unroll
            for (int c = 0; c < 4; c++)
                if (t0 + c < 30) h3[(o0 + a) * 30 + t0 + c] = acc[a][c];
        for (int v = tid; v < NCODE * 64; v += 256) cbs[v] = cb[v];
    }
    __syncthreads();

    // ---------- P4: VQ argmin (f64, exact for f32 inputs) ----------
    {
        float myd2 = 0.f;
        if (tid < 30) {
            const int i = tid;
            double d2[NCODE];
            #pragma unroll
            for (int c = 0; c < NCODE; c++) d2[c] = 0.0;
            for (int d = 0; d < 64; d++) {
                double v = (double)h3[d * 30 + i];
                #pragma unroll
                for (int c = 0; c < NCODE; c++) {
                    double df = v - (double)cbs[c * 64 + d];
                    d2[c] += df * df;
                }
            }
            int best = 0; double bd = d2[0];
            #pragma unroll
            for (int c = 1; c < NCODE; c++) if (d2[c] < bd) { bd = d2[c]; best = c; }
            codes[i] = best;
            myd2 = (float)bd;
        }
        float s = myd2;
        #pragma unroll
        for (int off = 32; off; off >>= 1) s += __shfl_down(s, off);
        if (tid == 0) loss_part[b] = s;
    }
    __syncthreads();

    // ---------- P5: encf/qf (f32, [i][d]), puzzles, decoder input ft[d][i] ----------
    {
        for (int v = tid; v < 30 * 64; v += 256) {
            int i = v >> 6, d = v & 63;
            float fv = h3[d * 30 + i];
            float qv = cbs[codes[i] * 64 + d];
            encf[v] = fv;
            qf[v]   = fv + (qv - fv);   // mirror straight-through expression
        }
        for (int v = tid; v < 900; v += 256)
            out[OFF_PUZ + b * 900 + v] = (float)codes[v / 30];
        for (int v = tid; v < 64 * 32; v += 256) {
            int d = v >> 5, i = v & 31;
            if (i < 30) {
                float fv = h3[d * 30 + i];
                float qv = cbs[codes[i] * 64 + d];
                ft[v] = fv + (qv - fv);
            } else ft[v] = 0.f;
        }
    }
    __syncthreads();

    // ---------- P6: features/quantized writes (float4) + convT1 (k3 s1 p0, 30->32, relu) ----------
    {
        float4* dF = ((float4*)(out + OFF_FEAT)) + b * 14400;
        float4* dQ = ((float4*)(out + OFF_Q))    + b * 14400;
        const float4* sE = (const float4*)encf;
        const float4* sQ = (const float4*)qf;
        for (int v = tid; v < 14400; v += 256) {
            int row = v >> 4, part = v & 15;   // row = i*30+j, part = d/4
            int i = row / 30;
            dF[v] = sE[i * 16 + part];
            dQ[v] = sQ[i * 16 + part];
        }
        const int o0 = (tid >> 3) * 2;
        const int t0 = (tid & 7) * 4;
        float acc[2][4];
        #pragma unroll
        for (int a = 0; a < 2; a++) {
            float bb = db1[o0 + a];
            #pragma unroll
            for (int c = 0; c < 4; c++) acc[a][c] = bb;
        }
        for (int i = 0; i < 64; i++) {
            #pragma unroll
            for (int kk = 0; kk < 3; kk++) {
                float wv[2], xv[4];
                #pragma unroll
                for (int a = 0; a < 2; a++) wv[a] = dw1[(i * 64 + o0 + a) * 3 + kk];
                #pragma unroll
                for (int c = 0; c < 4; c++) {
                    int s = t0 + c - kk;
                    xv[c] = (s >= 0 && s < 30) ? ft[i * 32 + s] : 0.f;
                }
                #pragma unroll
                for (int a = 0; a < 2; a++)
                    #pragma unroll
                    for (int c = 0; c < 4; c++)
                        acc[a][c] = fmaf(wv[a], xv[c], acc[a][c]);
            }
        }
        #pragma unroll
        for (int a = 0; a < 2; a++)
            #pragma unroll
            for (int c = 0; c < 4; c++)
                g1[(o0 + a) * 32 + t0 + c] = fmaxf(acc[a][c], 0.f);
    }
    __syncthreads();

    // ---------- P7: convT2 (k4 s2 p1, 32->64, relu): t = 2s-1+m ----------
    {
        const int o0 = (tid >> 3) * 2;
        const int t0 = (tid & 7) * 8;
        float acc[2][8];
        #pragma unroll
        for (int a = 0; a < 2; a++) {
            float bb = db2[o0 + a];
            #pragma unroll
            for (int c = 0; c < 8; c++) acc[a][c] = bb;
        }
        for (int i = 0; i < 64; i++) {
            float wv[2][4];
            #pragma unroll
            for (int a = 0; a < 2; a++)
                #pragma unroll
                for (int m = 0; m < 4; m++) wv[a][m] = dw2[(i * 64 + o0 + a) * 4 + m];
            #pragma unroll
            for (int c = 0; c < 8; c++) {
                int t = t0 + c;
                #pragma unroll
                for (int m = 0; m < 4; m++) {
                    int u = t + 1 - m;
                    if (u >= 0 && (u & 1) == 0 && (u >> 1) < 32) {
                        float xv = g1[i * 32 + (u >> 1)];
                        #pragma unroll
                        for (int a = 0; a < 2; a++)
                            acc[a][c] = fmaf(wv[a][m], xv, acc[a][c]);
                    }
                }
            }
        }
        #pragma unroll
        for (int a = 0; a < 2; a++)
            #pragma unroll
            for (int c = 0; c < 8; c++)
                g2[(o0 + a) * 64 + t0 + c] = fmaxf(acc[a][c], 0.f);
    }
    __syncthreads();

    // ---------- P8: convT3 (k4 s2 p1, 64len->128, 64->32ch, no relu) ----------
    {
        const int e  = tid >> 3;
        const int l0 = (tid & 7) * 16;
        float acc[16];
        {
            float bb = db3[e];
            #pragma unroll
            for (int c = 0; c < 16; c++) acc[c] = bb;
        }
        for (int i = 0; i < 64; i++) {
            float wv[4];
            #pragma unroll
            for (int m = 0; m < 4; m++) wv[m] = dw3[(i * 32 + e) * 4 + m];
            #pragma unroll
            for (int c = 0; c < 16; c++) {
                int l = l0 + c;
                #pragma unroll
                for (int m = 0; m < 4; m++) {
                    int u = l + 1 - m;
                    if (u >= 0 && (u & 1) == 0 && (u >> 1) < 64)
                        acc[c] = fmaf(wv[m], g2[i * 64 + (u >> 1)], acc[c]);
                }
            }
        }
        #pragma unroll
        for (int c = 0; c < 16; c++) dc[e * 128 + l0 + c] = acc[c];
    }
    __syncthreads();

    // ---------- P9a: stage out_w transposed [32][129] (conflict-free) & out_b ----------
    for (int v = tid; v < 128 * 32; v += 256)
        ows[(v & 31) * 129 + (v >> 5)] = ow[v];   // ows[e][vocab]
    if (tid < 128) obs[tid] = ob[tid];
    __syncthreads();

    // ---------- P9b: logits[l][v] = ob[v] + sum_e dc[e][l]*ow[v][e] ----------
    {
        const int vch = tid & 127;
        const int lh  = tid >> 7;       // 0 or 1
        float* outL = out + OFF_LOG + b * 16384;
        for (int ch = 0; ch < 8; ch++) {
            const int l = lh * 64 + ch * 8;
            float acc[8];
            float bb = obs[vch];
            #pragma unroll
            for (int c = 0; c < 8; c++) acc[c] = bb;
            for (int e = 0; e < 32; e++) {
                float w = ows[e * 129 + vch];
                const float4* dp = (const float4*)(dc + e * 128 + l);
                float4 d0 = dp[0], d1 = dp[1];
                acc[0] = fmaf(d0.x, w, acc[0]); acc[1] = fmaf(d0.y, w, acc[1]);
                acc[2] = fmaf(d0.z, w, acc[2]); acc[3] = fmaf(d0.w, w, acc[3]);
                acc[4] = fmaf(d1.x, w, acc[4]); acc[5] = fmaf(d1.y, w, acc[5]);
                acc[6] = fmaf(d1.z, w, acc[6]); acc[7] = fmaf(d1.w, w, acc[7]);
            }
            #pragma unroll
            for (int c = 0; c < 8; c++)
                outL[(l + c) * 128 + vch] = acc[c];
        }
    }
}

__global__ void loss_final(const float* __restrict__ part, float* __restrict__ out) {
    __shared__ float red[4];
    const int tid = threadIdx.x;
    float s = 0.f;
    for (int k = tid; k < NBATCH; k += 256) s += part[k];
    #pragma unroll
    for (int off = 32; off; off >>= 1) s += __shfl_down(s, off);
    if ((tid & 63) == 0) red[tid >> 6] = s;
    __syncthreads();
    if (tid == 0) {
        float t = red[0] + red[1] + red[2] + red[3];
        // vq_loss = 1.25 * sum(d2min) * 30 / (B*900*64) = 1.25*sum/3932160
        out[OFF_LOSS] = 1.25f * t / 3932160.0f;
    }
}

extern "C" void kernel_launch(void* const* d_in, const int* in_sizes, int n_in,
                              void* d_out, int out_size, void* d_ws, size_t ws_size,
                              hipStream_t stream) {
    const int*   tidx = (const int*)  d_in[0];
    const float* emb  = (const float*)d_in[1];
    const float* w1   = (const float*)d_in[2];
    const float* b1   = (const float*)d_in[3];
    const float* w2   = (const float*)d_in[4];
    const float* b2   = (const float*)d_in[5];
    const float* w3   = (const float*)d_in[6];
    const float* b3   = (const float*)d_in[7];
    const float* cb   = (const float*)d_in[8];
    const float* dw1  = (const float*)d_in[9];
    const float* db1  = (const float*)d_in[10];
    const float* dw2  = (const float*)d_in[11];
    const float* db2  = (const float*)d_in[12];
    const float* dw3  = (const float*)d_in[13];
    const float* db3  = (const float*)d_in[14];
    const float* ow   = (const float*)d_in[15];
    const float* ob   = (const float*)d_in[16];
    float* out  = (float*)d_out;
    float* part = (float*)d_ws;   // [2048] deterministic per-block loss partials

    vae_fused<<<NBATCH, 256, 0, stream>>>(tidx, emb, w1, b1, w2, b2, w3, b3, cb,
                                          dw1, db1, dw2, db2, dw3, db3, ow, ob,
                                          out, part);
    loss_final<<<1, 256, 0, stream>>>(part, out);
}

// Round 3
// 490.785 us; speedup vs baseline: 1.0181x; 1.0181x over previous
//
#include <hip/hip_runtime.h>

#define NBATCH 2048
#define SEQL   128
#define EMB    32
#define NCODE  10

// flat output offsets (f32 elements)
#define OFF_LOG  0
#define OFF_PUZ  33554432
#define OFF_FEAT 35397632
#define OFF_Q    153362432
#define OFF_LOSS 271327232

// packed-weight offsets in d_ws (floats)
#define WP_W1   0        // [32i][3k][64o]
#define WP_W2   6144     // [64i][3k][64o]
#define WP_W3   18432    // [64i][3k][64o]
#define WP_DW1  30720    // [64i][3k][64o]
#define WP_END  43008
#define WS_LOSS 43008    // [2048] partials

// LDS layout (byte offsets into sm[33920]), phase-checked liveness:
//  xs   [32][129] @0      (P0-P1)
//  h1   [64][64]  @16512  (P1-P2)
//  h2   [64][32]  @0      (P2-P3)
//  h3   [64][30]  @8192   (P3-P5)
//  cbs  [10][64]  @15872  (P3-P5)
//  codes[30]      @18432  (P4-P5)
//  encf [30][64]  @18560  (P5-P6)
//  qf   [30][64]  @26240  (P5-P6)
//  ft   [64][32]  @0      (P5-P6)
//  g1   [64][32]  @8192   (P6-P7)
//  g2   [64][64]  @16384  (P7-P8)
//  dc   [32][128] @0      (P8-P9)
//  ows  [32][129] @16512  (P9)
//  obs  [128]     @33024  (P9)

__global__ void prep_weights(const float* __restrict__ w1, const float* __restrict__ w2,
                             const float* __restrict__ w3, const float* __restrict__ dw1,
                             float* __restrict__ wp)
{
    int idx = blockIdx.x * 256 + threadIdx.x;
    if (idx < 6144) {                       // w1p[i][k][o] <- w1[o][i][k], i<32
        int o = idx & 63, r = idx >> 6;     // r = i*3+kk
        int kk = r % 3, i = r / 3;
        wp[idx] = w1[(o * 32 + i) * 3 + kk];
    } else if (idx < 18432) {               // w2p
        int t = idx - 6144;
        int o = t & 63, r = t >> 6;
        int kk = r % 3, i = r / 3;
        wp[idx] = w2[(o * 64 + i) * 3 + kk];
    } else if (idx < 30720) {               // w3p
        int t = idx - 18432;
        int o = t & 63, r = t >> 6;
        int kk = r % 3, i = r / 3;
        wp[idx] = w3[(o * 64 + i) * 3 + kk];
    } else if (idx < 43008) {               // dw1p[i][k][o] <- dw1[i][o][k]
        int t = idx - 30720;
        int o = t & 63, r = t >> 6;
        int kk = r % 3, i = r / 3;
        wp[idx] = dw1[(i * 64 + o) * 3 + kk];
    }
}

__global__ __launch_bounds__(256, 4)
void vae_fused(const int* __restrict__ tidx, const float* __restrict__ emb,
               const float* __restrict__ b1, const float* __restrict__ b2,
               const float* __restrict__ b3, const float* __restrict__ cb,
               const float* __restrict__ db1,
               const float* __restrict__ dw2, const float* __restrict__ db2,
               const float* __restrict__ dw3, const float* __restrict__ db3,
               const float* __restrict__ ow, const float* __restrict__ ob,
               const float* __restrict__ wp,
               float* __restrict__ out, float* __restrict__ loss_part)
{
    __shared__ char sm[33920];
    float* xs   = (float*)(sm);            // [32][129]
    float* h1   = (float*)(sm + 16512);    // [64][64]
    float* h2   = (float*)(sm);            // [64][32]
    float* h3   = (float*)(sm + 8192);     // [64][30]
    float* cbs  = (float*)(sm + 15872);    // [10][64]
    int*   codes= (int*)  (sm + 18432);    // [30]
    float* encf = (float*)(sm + 18560);    // [30][64]
    float* qf   = (float*)(sm + 26240);    // [30][64]
    float* ft   = (float*)(sm);            // [64][32]
    float* g1   = (float*)(sm + 8192);     // [64][32]
    float* g2   = (float*)(sm + 16384);    // [64][64]
    float* dc   = (float*)(sm);            // [32][128]
    float* ows  = (float*)(sm + 16512);    // [32][129]
    float* obs  = (float*)(sm + 33024);    // [128]

    const int b   = blockIdx.x;
    const int tid = threadIdx.x;
    const int* ti = tidx + b * SEQL;

    // ---------- P0: coalesced embedding gather  xs[e][l] = emb[ti[l]][e] ----------
    for (int v = tid; v < EMB * SEQL; v += 256) {
        int l = v >> 5, e = v & 31;            // 32 consecutive lanes read 128B of emb
        xs[e * 129 + l] = emb[ti[l] * EMB + e];
    }
    __syncthreads();

    // ---------- P1: conv1 32->64ch, L128->64, k3 s2 p1, relu ----------
    {
        const int og = tid >> 4;           // 16 groups of 4 out-ch
        const int o0 = og * 4;
        const int ln = tid & 15;           // cols ln+16c (stride-2 LDS reads: conflict-free)
        float acc[4][4];
        #pragma unroll
        for (int a = 0; a < 4; a++) {
            float bb = b1[o0 + a];
            #pragma unroll
            for (int c = 0; c < 4; c++) acc[a][c] = bb;
        }
        const float4* w1v = (const float4*)(wp + WP_W1);
        #pragma unroll 2
        for (int i = 0; i < 32; i++) {
            #pragma unroll
            for (int kk = 0; kk < 3; kk++) {
                float4 wv4 = w1v[(i * 3 + kk) * 16 + og];
                const float* wv = (const float*)&wv4;
                #pragma unroll
                for (int c = 0; c < 4; c++) {
                    int l = 2 * (ln + 16 * c) + kk - 1;
                    float xv = (l >= 0 && l < 128) ? xs[i * 129 + l] : 0.f;
                    #pragma unroll
                    for (int a = 0; a < 4; a++)
                        acc[a][c] = fmaf(wv[a], xv, acc[a][c]);
                }
            }
        }
        #pragma unroll
        for (int a = 0; a < 4; a++)
            #pragma unroll
            for (int c = 0; c < 4; c++)
                h1[(o0 + a) * 64 + ln + 16 * c] = fmaxf(acc[a][c], 0.f);
    }
    __syncthreads();

    // ---------- P2: conv2 64->64ch, 64->32, k3 s2 p1, relu ----------
    {
        const int og = tid >> 3;           // 32 groups of 2 out-ch
        const int o0 = og * 2;
        const int ln = tid & 7;            // cols ln+8c
        float acc[2][4];
        #pragma unroll
        for (int a = 0; a < 2; a++) {
            float bb = b2[o0 + a];
            #pragma unroll
            for (int c = 0; c < 4; c++) acc[a][c] = bb;
        }
        const float2* w2v = (const float2*)(wp + WP_W2);
        #pragma unroll 2
        for (int i = 0; i < 64; i++) {
            #pragma unroll
            for (int kk = 0; kk < 3; kk++) {
                float2 wv = w2v[(i * 3 + kk) * 32 + og];
                #pragma unroll
                for (int c = 0; c < 4; c++) {
                    int l = 2 * (ln + 8 * c) + kk - 1;
                    float xv = (l >= 0 && l < 64) ? h1[i * 64 + l] : 0.f;
                    acc[0][c] = fmaf(wv.x, xv, acc[0][c]);
                    acc[1][c] = fmaf(wv.y, xv, acc[1][c]);
                }
            }
        }
        #pragma unroll
        for (int a = 0; a < 2; a++)
            #pragma unroll
            for (int c = 0; c < 4; c++)
                h2[(o0 + a) * 32 + ln + 8 * c] = fmaxf(acc[a][c], 0.f);
    }
    __syncthreads();

    // ---------- P3: conv3 64->64ch, 32->30, k3 s1 p0 (no relu); load codebook ----------
    {
        const int og = tid >> 3;
        const int o0 = og * 2;
        const int ln = tid & 7;
        float acc[2][4];
        #pragma unroll
        for (int a = 0; a < 2; a++) {
            float bb = b3[o0 + a];
            #pragma unroll
            for (int c = 0; c < 4; c++) acc[a][c] = bb;
        }
        const float2* w3v = (const float2*)(wp + WP_W3);
        #pragma unroll 2
        for (int i = 0; i < 64; i++) {
            #pragma unroll
            for (int kk = 0; kk < 3; kk++) {
                float2 wv = w3v[(i * 3 + kk) * 32 + og];
                #pragma unroll
                for (int c = 0; c < 4; c++) {
                    int l = ln + 8 * c + kk;
                    float xv = (l < 32) ? h2[i * 32 + l] : 0.f;
                    acc[0][c] = fmaf(wv.x, xv, acc[0][c]);
                    acc[1][c] = fmaf(wv.y, xv, acc[1][c]);
                }
            }
        }
        #pragma unroll
        for (int a = 0; a < 2; a++)
            #pragma unroll
            for (int c = 0; c < 4; c++) {
                int col = ln + 8 * c;
                if (col < 30) h3[(o0 + a) * 30 + col] = acc[a][c];
            }
        for (int v = tid; v < NCODE * 64; v += 256) cbs[v] = cb[v];
    }
    __syncthreads();

    // ---------- P4: VQ argmin (f64, exact for f32 inputs) ----------
    {
        float myd2 = 0.f;
        if (tid < 30) {
            const int i = tid;
            double d2[NCODE];
            #pragma unroll
            for (int c = 0; c < NCODE; c++) d2[c] = 0.0;
            for (int d = 0; d < 64; d++) {
                double v = (double)h3[d * 30 + i];
                #pragma unroll
                for (int c = 0; c < NCODE; c++) {
                    double df = v - (double)cbs[c * 64 + d];
                    d2[c] += df * df;
                }
            }
            int best = 0; double bd = d2[0];
            #pragma unroll
            for (int c = 1; c < NCODE; c++) if (d2[c] < bd) { bd = d2[c]; best = c; }
            codes[i] = best;
            myd2 = (float)bd;
        }
        float s = myd2;
        #pragma unroll
        for (int off = 32; off; off >>= 1) s += __shfl_down(s, off);
        if (tid == 0) loss_part[b] = s;
    }
    __syncthreads();

    // ---------- P5: encf/qf ([i][d] f32), puzzles, decoder input ft[d][i] ----------
    {
        for (int v = tid; v < 30 * 64; v += 256) {
            int i = v >> 6, d = v & 63;
            float fv = h3[d * 30 + i];
            float qv = cbs[codes[i] * 64 + d];
            encf[v] = fv;
            qf[v]   = fv + (qv - fv);   // mirror straight-through expression
        }
        for (int v = tid; v < 900; v += 256)
            out[OFF_PUZ + b * 900 + v] = (float)codes[v / 30];
        for (int v = tid; v < 64 * 32; v += 256) {
            int d = v >> 5, i = v & 31;
            if (i < 30) {
                float fv = h3[d * 30 + i];
                float qv = cbs[codes[i] * 64 + d];
                ft[v] = fv + (qv - fv);
            } else ft[v] = 0.f;
        }
    }
    __syncthreads();

    // ---------- P6: features/quantized float4 writes + convT1 (k3 s1 p0, 30->32, relu) ----------
    {
        float4* dF = ((float4*)(out + OFF_FEAT)) + b * 14400;
        float4* dQ = ((float4*)(out + OFF_Q))    + b * 14400;
        const float4* sE = (const float4*)encf;
        const float4* sQ = (const float4*)qf;
        for (int v = tid; v < 14400; v += 256) {
            int row = v >> 4, part = v & 15;   // row = i*30+j, part = d/4
            int i = row / 30;
            dF[v] = sE[i * 16 + part];
            dQ[v] = sQ[i * 16 + part];
        }
        const int og = tid >> 3;
        const int o0 = og * 2;
        const int ln = tid & 7;
        float acc[2][4];
        #pragma unroll
        for (int a = 0; a < 2; a++) {
            float bb = db1[o0 + a];
            #pragma unroll
            for (int c = 0; c < 4; c++) acc[a][c] = bb;
        }
        const float2* dw1v = (const float2*)(wp + WP_DW1);
        #pragma unroll 2
        for (int i = 0; i < 64; i++) {
            #pragma unroll
            for (int kk = 0; kk < 3; kk++) {
                float2 wv = dw1v[(i * 3 + kk) * 32 + og];
                #pragma unroll
                for (int c = 0; c < 4; c++) {
                    int s = ln + 8 * c - kk;
                    float xv = (s >= 0 && s < 30) ? ft[i * 32 + s] : 0.f;
                    acc[0][c] = fmaf(wv.x, xv, acc[0][c]);
                    acc[1][c] = fmaf(wv.y, xv, acc[1][c]);
                }
            }
        }
        #pragma unroll
        for (int a = 0; a < 2; a++)
            #pragma unroll
            for (int c = 0; c < 4; c++)
                g1[(o0 + a) * 32 + ln + 8 * c] = fmaxf(acc[a][c], 0.f);
    }
    __syncthreads();

    // ---------- P7: convT2 (k4 s2 p1, 32->64, relu): parity folds at compile time ----------
    {
        const int o0 = (tid >> 3) * 2;
        const int t0 = (tid & 7) * 8;
        float acc[2][8];
        #pragma unroll
        for (int a = 0; a < 2; a++) {
            float bb = db2[o0 + a];
            #pragma unroll
            for (int c = 0; c < 8; c++) acc[a][c] = bb;
        }
        const float4* dw2v = (const float4*)dw2;   // dw2 is [i][o][4] already
        #pragma unroll 2
        for (int i = 0; i < 64; i++) {
            float4 wa4 = dw2v[i * 64 + o0];
            float4 wb4 = dw2v[i * 64 + o0 + 1];
            const float* wa = (const float*)&wa4;
            const float* wb = (const float*)&wb4;
            #pragma unroll
            for (int c = 0; c < 8; c++) {
                int t = t0 + c;
                #pragma unroll
                for (int m = 0; m < 4; m++) {
                    int u = t + 1 - m;
                    if (u >= 0 && (u & 1) == 0 && (u >> 1) < 32) {
                        float xv = g1[i * 32 + (u >> 1)];
                        acc[0][c] = fmaf(wa[m], xv, acc[0][c]);
                        acc[1][c] = fmaf(wb[m], xv, acc[1][c]);
                    }
                }
            }
        }
        #pragma unroll
        for (int a = 0; a < 2; a++)
            #pragma unroll
            for (int c = 0; c < 8; c++)
                g2[(o0 + a) * 64 + t0 + c] = fmaxf(acc[a][c], 0.f);
    }
    __syncthreads();

    // ---------- P8: convT3 (k4 s2 p1, 64len->128, 64->32ch, no relu) ----------
    {
        const int e  = tid >> 3;
        const int l0 = (tid & 7) * 16;
        float acc[16];
        {
            float bb = db3[e];
            #pragma unroll
            for (int c = 0; c < 16; c++) acc[c] = bb;
        }
        const float4* dw3v = (const float4*)dw3;   // dw3 is [i][o][4] already
        #pragma unroll 2
        for (int i = 0; i < 64; i++) {
            float4 wv4 = dw3v[i * 32 + e];
            const float* wv = (const float*)&wv4;
            #pragma unroll
            for (int c = 0; c < 16; c++) {
                int l = l0 + c;
                #pragma unroll
                for (int m = 0; m < 4; m++) {
                    int u = l + 1 - m;
                    if (u >= 0 && (u & 1) == 0 && (u >> 1) < 64)
                        acc[c] = fmaf(wv[m], g2[i * 64 + (u >> 1)], acc[c]);
                }
            }
        }
        #pragma unroll
        for (int c = 0; c < 16; c++) dc[e * 128 + l0 + c] = acc[c];
    }
    __syncthreads();

    // ---------- P9a: stage out_w transposed [32][129] & out_b ----------
    for (int v = tid; v < 128 * 32; v += 256)
        ows[(v & 31) * 129 + (v >> 5)] = ow[v];   // ows[e][vocab]
    if (tid < 128) obs[tid] = ob[tid];
    __syncthreads();

    // ---------- P9b: logits[l][v] = ob[v] + sum_e dc[e][l]*ow[v][e] ----------
    {
        const int vch = tid & 127;
        const int lh  = tid >> 7;       // 0 or 1
        float* outL = out + OFF_LOG + b * 16384;
        for (int ch = 0; ch < 8; ch++) {
            const int l = lh * 64 + ch * 8;
            float acc[8];
            float bb = obs[vch];
            #pragma unroll
            for (int c = 0; c < 8; c++) acc[c] = bb;
            #pragma unroll 4
            for (int e = 0; e < 32; e++) {
                float w = ows[e * 129 + vch];
                const float4* dp = (const float4*)(dc + e * 128 + l);
                float4 d0 = dp[0], d1 = dp[1];
                acc[0] = fmaf(d0.x, w, acc[0]); acc[1] = fmaf(d0.y, w, acc[1]);
                acc[2] = fmaf(d0.z, w, acc[2]); acc[3] = fmaf(d0.w, w, acc[3]);
                acc[4] = fmaf(d1.x, w, acc[4]); acc[5] = fmaf(d1.y, w, acc[5]);
                acc[6] = fmaf(d1.z, w, acc[6]); acc[7] = fmaf(d1.w, w, acc[7]);
            }
            #pragma unroll
            for (int c = 0; c < 8; c++)
                outL[(l + c) * 128 + vch] = acc[c];
        }
    }
}

__global__ void loss_final(const float* __restrict__ part, float* __restrict__ out) {
    __shared__ float red[4];
    const int tid = threadIdx.x;
    float s = 0.f;
    for (int k = tid; k < NBATCH; k += 256) s += part[k];
    #pragma unroll
    for (int off = 32; off; off >>= 1) s += __shfl_down(s, off);
    if ((tid & 63) == 0) red[tid >> 6] = s;
    __syncthreads();
    if (tid == 0) {
        float t = red[0] + red[1] + red[2] + red[3];
        // vq_loss = 1.25 * sum(d2min) * 30 / (B*900*64) = 1.25*sum/3932160
        out[OFF_LOSS] = 1.25f * t / 3932160.0f;
    }
}

extern "C" void kernel_launch(void* const* d_in, const int* in_sizes, int n_in,
                              void* d_out, int out_size, void* d_ws, size_t ws_size,
                              hipStream_t stream) {
    const int*   tidx = (const int*)  d_in[0];
    const float* emb  = (const float*)d_in[1];
    const float* w1   = (const float*)d_in[2];
    const float* b1   = (const float*)d_in[3];
    const float* w2   = (const float*)d_in[4];
    const float* b2   = (const float*)d_in[5];
    const float* w3   = (const float*)d_in[6];
    const float* b3   = (const float*)d_in[7];
    const float* cb   = (const float*)d_in[8];
    const float* dw1  = (const float*)d_in[9];
    const float* db1  = (const float*)d_in[10];
    const float* dw2  = (const float*)d_in[11];
    const float* db2  = (const float*)d_in[12];
    const float* dw3  = (const float*)d_in[13];
    const float* db3  = (const float*)d_in[14];
    const float* ow   = (const float*)d_in[15];
    const float* ob   = (const float*)d_in[16];
    float* out = (float*)d_out;
    float* wp  = (float*)d_ws;                 // packed weights
    float* part = wp + WS_LOSS;                // [2048] loss partials

    prep_weights<<<168, 256, 0, stream>>>(w1, w2, w3, dw1, wp);
    vae_fused<<<NBATCH, 256, 0, stream>>>(tidx, emb, b1, b2, b3, cb, db1,
                                          dw2, db2, dw3, db3, ow, ob, wp,
                                          out, part);
    loss_final<<<1, 256, 0, stream>>>(part, out);
}

// Round 4
// 291.926 us; speedup vs baseline: 1.7117x; 1.6812x over previous
//
#include <hip/hip_runtime.h>
#include <hip/hip_bf16.h>

#define NBATCH 2048
#define SEQL   128
#define EMB    32
#define NCODE  10

// flat output offsets (f32 elements)
#define OFF_LOG  0
#define OFF_PUZ  33554432
#define OFF_FEAT 35397632
#define OFF_Q    153362432
#define OFF_LOSS 271327232

// f32 packed-weight offsets in d_ws (float elements)
#define WP_W1   0        // [32i][3k][64o]
#define WP_W2   6144     // [64i][3k][64o]
#define WP_W3   18432    // [64i][3k][64o]
#define WP_F32_END 30720 // = 122880 bytes

// bf16 packed-weight offsets (ushort elements, base = d_ws + 122880B)
#define WH_W6   0        // [64o][200] k=kk*64+i (192 valid)
#define WH_W7E  12800    // [64o][136] k=kb*64+i; kb0:m=1, kb1:m=3
#define WH_W7O  21504    // [64o][136] kb0:m=0, kb1:m=2
#define WH_W8E  30208    // [32o][136] kb0:m=1, kb1:m=3
#define WH_W8O  34560    // [32o][136] kb0:m=0, kb1:m=2
#define WH_OW   38912    // [128v][40] e (32 valid)
#define WH_END  44032
#define WS_LOSS_BYTES 210944   // loss partials f32 [2048]

typedef __attribute__((ext_vector_type(8))) short short8v;
typedef __attribute__((ext_vector_type(4))) float f32x4;

static __device__ __forceinline__ unsigned short f2bfu(float f) {
    __hip_bfloat16 h = __float2bfloat16(f);
    unsigned short u; __builtin_memcpy(&u, &h, 2); return u;
}

static __device__ __forceinline__ f32x4 mfma16(short8v a, short8v b, f32x4 c) {
    return __builtin_amdgcn_mfma_f32_16x16x32_bf16(a, b, c, 0, 0, 0);
}

__global__ void prep_weights(const float* __restrict__ w1, const float* __restrict__ w2,
                             const float* __restrict__ w3, const float* __restrict__ dw1,
                             const float* __restrict__ dw2, const float* __restrict__ dw3,
                             const float* __restrict__ ow,
                             float* __restrict__ wp, unsigned short* __restrict__ wph)
{
    int idx = blockIdx.x * 256 + threadIdx.x;
    if (idx < 6144) {                       // w1p[i][k][o] <- w1[o][i][k]
        int o = idx & 63, r = idx >> 6, kk = r % 3, i = r / 3;
        wp[WP_W1 + idx] = w1[(o * 32 + i) * 3 + kk];
    } else if (idx < 18432) {               // w2p
        int t = idx - 6144;
        int o = t & 63, r = t >> 6, kk = r % 3, i = r / 3;
        wp[WP_W2 + t] = w2[(o * 64 + i) * 3 + kk];
    } else if (idx < 30720) {               // w3p
        int t = idx - 18432;
        int o = t & 63, r = t >> 6, kk = r % 3, i = r / 3;
        wp[WP_W3 + t] = w3[(o * 64 + i) * 3 + kk];
    } else if (idx < 30720 + WH_END) {      // bf16 packs
        int t = idx - 30720;
        float v = 0.f;
        if (t < WH_W7E) {                           // W6: convT1
            int o = t / 200, k = t % 200;
            if (k < 192) v = dw1[((k & 63) * 64 + o) * 3 + (k >> 6)];
        } else if (t < WH_W7O) {                    // W7E
            int s = t - WH_W7E; int o = s / 136, k = s % 136;
            if (k < 128) v = dw2[((k & 63) * 64 + o) * 4 + ((k >> 6) ? 3 : 1)];
        } else if (t < WH_W8E) {                    // W7O
            int s = t - WH_W7O; int o = s / 136, k = s % 136;
            if (k < 128) v = dw2[((k & 63) * 64 + o) * 4 + ((k >> 6) ? 2 : 0)];
        } else if (t < WH_W8O) {                    // W8E
            int s = t - WH_W8E; int o = s / 136, k = s % 136;
            if (k < 128) v = dw3[((k & 63) * 32 + o) * 4 + ((k >> 6) ? 3 : 1)];
        } else if (t < WH_OW) {                     // W8O
            int s = t - WH_W8O; int o = s / 136, k = s % 136;
            if (k < 128) v = dw3[((k & 63) * 32 + o) * 4 + ((k >> 6) ? 2 : 0)];
        } else {                                    // OW
            int s = t - WH_OW; int vv = s / 40, e = s % 40;
            if (e < 32) v = ow[vv * 32 + e];
        }
        wph[t] = f2bfu(v);
    }
}

// LDS (bytes into sm[34688]), liveness-checked:
//  xs  [32][130] f32 @0      (P0-P1)   halo col 0 = zero
//  h1  [64][66]  f32 @16640  (P1-P2)   halo col 0 = zero
//  h2  [64][34]  f32 @0      (P2-P3)   cols 32,33 = zero
//  h3  [64][30]  f32 @8704   (P3-P5)
//  cbs [10][64]  f32 @16640  (P3-P5)
//  codes[30]     i32 @19200  (P4-P5)
//  encf[30][64]  f32 @19328  (P5-P6)
//  qf  [30][64]  f32 @27008  (P5-P6)
//  Xq  [34][72]  b16 @0      (P5-P6)   rows 0,1,32,33 zero (pos -2..31)
//  X7  [34][72]  b16 @4896   (P6-P7)   rows 0,33 zero (pos -1..32)
//  X8  [66][72]  b16 @9792   (P7-P8)   rows 0,65 zero (pos -1..64)
//  Xd  [128][40] b16 @19296  (P8-P9)

__global__ __launch_bounds__(256, 4)
void vae_fused(const int* __restrict__ tidx, const float* __restrict__ emb,
               const float* __restrict__ b1, const float* __restrict__ b2,
               const float* __restrict__ b3, const float* __restrict__ cb,
               const float* __restrict__ db1, const float* __restrict__ db2,
               const float* __restrict__ db3, const float* __restrict__ ob,
               const float* __restrict__ wp, const unsigned short* __restrict__ wph,
               float* __restrict__ out, float* __restrict__ loss_part)
{
    __shared__ __align__(16) char sm[34688];
    float* xs   = (float*)(sm);            // [32][130]
    float* h1   = (float*)(sm + 16640);    // [64][66]
    float* h2   = (float*)(sm);            // [64][34]
    float* h3   = (float*)(sm + 8704);     // [64][30]
    float* cbs  = (float*)(sm + 16640);    // [10][64]
    int*   codes= (int*)  (sm + 19200);    // [30]
    float* encf = (float*)(sm + 19328);    // [30][64]
    float* qf   = (float*)(sm + 27008);    // [30][64]
    unsigned short* Xq = (unsigned short*)(sm);          // [34][72]
    unsigned short* X7 = (unsigned short*)(sm + 4896);   // [34][72]
    unsigned short* X8 = (unsigned short*)(sm + 9792);   // [66][72]
    unsigned short* Xd = (unsigned short*)(sm + 19296);  // [128][40]

    const int b   = blockIdx.x;
    const int tid = threadIdx.x;
    const int* ti = tidx + b * SEQL;

    const int lane = tid & 63, wid = tid >> 6;
    const int lr = lane & 15, lk8 = (lane >> 4) * 8;
    const int rquad = (lane >> 4) * 4;

    // ---------- P0: coalesced embedding gather  xs[e][1+l] = emb[ti[l]][e] ----------
    for (int v = tid; v < EMB * SEQL; v += 256) {
        int l = v >> 5, e = v & 31;
        xs[e * 130 + 1 + l] = emb[ti[l] * EMB + e];
    }
    if (tid < 32) xs[tid * 130] = 0.f;
    __syncthreads();

    // ---------- P1: conv1 32->64ch, L128->64, k3 s2 p1, relu (halo: no checks) ----------
    {
        const int og = tid >> 4, o0 = og * 4;
        const int ln = tid & 15;
        float acc[4][4];
        #pragma unroll
        for (int a = 0; a < 4; a++) {
            float bb = b1[o0 + a];
            #pragma unroll
            for (int c = 0; c < 4; c++) acc[a][c] = bb;
        }
        const float4* w1v = (const float4*)(wp + WP_W1);
        #pragma unroll 2
        for (int i = 0; i < 32; i++) {
            #pragma unroll
            for (int kk = 0; kk < 3; kk++) {
                float4 wv4 = w1v[(i * 3 + kk) * 16 + og];
                const float* wv = (const float*)&wv4;
                #pragma unroll
                for (int c = 0; c < 4; c++) {
                    float xv = xs[i * 130 + 2 * (ln + 16 * c) + kk];
                    #pragma unroll
                    for (int a = 0; a < 4; a++)
                        acc[a][c] = fmaf(wv[a], xv, acc[a][c]);
                }
            }
        }
        #pragma unroll
        for (int a = 0; a < 4; a++)
            #pragma unroll
            for (int c = 0; c < 4; c++)
                h1[(o0 + a) * 66 + 1 + ln + 16 * c] = fmaxf(acc[a][c], 0.f);
        if (tid < 64) h1[tid * 66] = 0.f;
    }
    __syncthreads();

    // ---------- P2: conv2 64->64ch, 64->32, k3 s2 p1, relu ----------
    {
        const int og = tid >> 3, o0 = og * 2;
        const int ln = tid & 7;
        float acc[2][4];
        #pragma unroll
        for (int a = 0; a < 2; a++) {
            float bb = b2[o0 + a];
            #pragma unroll
            for (int c = 0; c < 4; c++) acc[a][c] = bb;
        }
        const float2* w2v = (const float2*)(wp + WP_W2);
        #pragma unroll 2
        for (int i = 0; i < 64; i++) {
            #pragma unroll
            for (int kk = 0; kk < 3; kk++) {
                float2 wv = w2v[(i * 3 + kk) * 32 + og];
                #pragma unroll
                for (int c = 0; c < 4; c++) {
                    float xv = h1[i * 66 + 2 * (ln + 8 * c) + kk];
                    acc[0][c] = fmaf(wv.x, xv, acc[0][c]);
                    acc[1][c] = fmaf(wv.y, xv, acc[1][c]);
                }
            }
        }
        #pragma unroll
        for (int a = 0; a < 2; a++)
            #pragma unroll
            for (int c = 0; c < 4; c++)
                h2[(o0 + a) * 34 + ln + 8 * c] = fmaxf(acc[a][c], 0.f);
        if (tid < 64) { h2[tid * 34 + 32] = 0.f; h2[tid * 34 + 33] = 0.f; }
    }
    __syncthreads();

    // ---------- P3: conv3 64->64ch, 32->30, k3 s1 p0 (no relu); load codebook ----------
    {
        const int og = tid >> 3, o0 = og * 2;
        const int ln = tid & 7;
        float acc[2][4];
        #pragma unroll
        for (int a = 0; a < 2; a++) {
            float bb = b3[o0 + a];
            #pragma unroll
            for (int c = 0; c < 4; c++) acc[a][c] = bb;
        }
        const float2* w3v = (const float2*)(wp + WP_W3);
        #pragma unroll 2
        for (int i = 0; i < 64; i++) {
            #pragma unroll
            for (int kk = 0; kk < 3; kk++) {
                float2 wv = w3v[(i * 3 + kk) * 32 + og];
                #pragma unroll
                for (int c = 0; c < 4; c++) {
                    float xv = h2[i * 34 + ln + 8 * c + kk];
                    acc[0][c] = fmaf(wv.x, xv, acc[0][c]);
                    acc[1][c] = fmaf(wv.y, xv, acc[1][c]);
                }
            }
        }
        #pragma unroll
        for (int a = 0; a < 2; a++)
            #pragma unroll
            for (int c = 0; c < 4; c++) {
                int col = ln + 8 * c;
                if (col < 30) h3[(o0 + a) * 30 + col] = acc[a][c];
            }
        for (int v = tid; v < NCODE * 64; v += 256) cbs[v] = cb[v];
    }
    __syncthreads();

    // ---------- P4: VQ argmin (f64, exact for f32 inputs) ----------
    {
        float myd2 = 0.f;
        if (tid < 30) {
            const int i = tid;
            double d2[NCODE];
            #pragma unroll
            for (int c = 0; c < NCODE; c++) d2[c] = 0.0;
            for (int d = 0; d < 64; d++) {
                double v = (double)h3[d * 30 + i];
                #pragma unroll
                for (int c = 0; c < NCODE; c++) {
                    double df = v - (double)cbs[c * 64 + d];
                    d2[c] += df * df;
                }
            }
            int best = 0; double bd = d2[0];
            #pragma unroll
            for (int c = 1; c < NCODE; c++) if (d2[c] < bd) { bd = d2[c]; best = c; }
            codes[i] = best;
            myd2 = (float)bd;
        }
        float s = myd2;
        #pragma unroll
        for (int off = 32; off; off >>= 1) s += __shfl_down(s, off);
        if (tid == 0) loss_part[b] = s;
    }
    __syncthreads();

    // ---------- P5: encf/qf f32, puzzles, Xq bf16 [pos+2][ch] ----------
    {
        for (int v = tid; v < 30 * 64; v += 256) {
            int i = v >> 6, d = v & 63;
            float fv = h3[d * 30 + i];
            float qv = cbs[codes[i] * 64 + d];
            float sv = fv + (qv - fv);      // straight-through value
            encf[v] = fv;
            qf[v]   = sv;
            Xq[(i + 2) * 72 + d] = f2bfu(sv);
        }
        for (int v = tid; v < 900; v += 256)
            out[OFF_PUZ + b * 900 + v] = (float)codes[v / 30];
        for (int v = tid; v < 4 * 72; v += 256) {
            int rr = v / 72, c = v % 72;
            int row = (rr < 2) ? rr : rr + 30;      // rows 0,1,32,33
            Xq[row * 72 + c] = 0;
        }
    }
    __syncthreads();

    // ---------- P6: features/quantized float4 writes + MFMA convT1 (K=192) -> X7 ----------
    {
        float4* dF = ((float4*)(out + OFF_FEAT)) + b * 14400;
        float4* dQ = ((float4*)(out + OFF_Q))    + b * 14400;
        const float4* sE = (const float4*)encf;
        const float4* sQ = (const float4*)qf;
        for (int v = tid; v < 14400; v += 256) {
            int row = v >> 4, part = v & 15;
            int i = row / 30;
            dF[v] = sE[i * 16 + part];
            dQ[v] = sQ[i * 16 + part];
        }
        for (int v = tid; v < 2 * 72; v += 256) {
            int rr = v / 72, c = v % 72;
            X7[(rr ? 33 : 0) * 72 + c] = 0;
        }
        const unsigned short* w6p = wph + WH_W6;
        #pragma unroll
        for (int q = 0; q < 2; q++) {
            int T = wid * 2 + q;
            int m0 = (T >> 2) * 16, o0 = (T & 3) * 16;
            f32x4 acc;
            float bias = db1[o0 + lr];
            acc[0] = acc[1] = acc[2] = acc[3] = bias;
            #pragma unroll
            for (int kk = 0; kk < 3; kk++)
                #pragma unroll
                for (int k2 = 0; k2 < 2; k2++) {
                    short8v a = *(const short8v*)&Xq[(m0 + lr - kk + 2) * 72 + k2 * 32 + lk8];
                    short8v w = *(const short8v*)&w6p[(o0 + lr) * 200 + kk * 64 + k2 * 32 + lk8];
                    acc = mfma16(a, w, acc);
                }
            #pragma unroll
            for (int r = 0; r < 4; r++) {
                int t = m0 + rquad + r;
                X7[(t + 1) * 72 + o0 + lr] = f2bfu(fmaxf(acc[r], 0.f));
            }
        }
    }
    __syncthreads();

    // ---------- P7: MFMA convT2 (parity GEMMs, K=128) -> X8 ----------
    {
        for (int v = tid; v < 2 * 72; v += 256) {
            int rr = v / 72, c = v % 72;
            X8[(rr ? 65 : 0) * 72 + c] = 0;
        }
        #pragma unroll
        for (int q = 0; q < 4; q++) {
            int T = wid * 4 + q;            // 0..15
            int p  = T >> 3;
            int m0 = ((T >> 2) & 1) * 16, o0 = (T & 3) * 16;
            const unsigned short* wb = wph + (p ? WH_W7O : WH_W7E);
            f32x4 acc;
            float bias = db2[o0 + lr];
            acc[0] = acc[1] = acc[2] = acc[3] = bias;
            int rb0 = p ? 2 : 1, rb1 = p ? 1 : 0;
            #pragma unroll
            for (int kb = 0; kb < 2; kb++) {
                int rbase = kb ? rb1 : rb0;
                #pragma unroll
                for (int k2 = 0; k2 < 2; k2++) {
                    short8v a = *(const short8v*)&X7[(m0 + lr + rbase) * 72 + k2 * 32 + lk8];
                    short8v w = *(const short8v*)&wb[(o0 + lr) * 136 + kb * 64 + k2 * 32 + lk8];
                    acc = mfma16(a, w, acc);
                }
            }
            #pragma unroll
            for (int r = 0; r < 4; r++) {
                int t = 2 * (m0 + rquad + r) + p;
                X8[(t + 1) * 72 + o0 + lr] = f2bfu(fmaxf(acc[r], 0.f));
            }
        }
    }
    __syncthreads();

    // ---------- P8: MFMA convT3 (parity GEMMs, K=128) -> Xd [l][e] ----------
    {
        #pragma unroll
        for (int q = 0; q < 4; q++) {
            int T = wid * 4 + q;            // 0..15
            int p  = T >> 3;
            int m0 = ((T >> 1) & 3) * 16, o0 = (T & 1) * 16;
            const unsigned short* wb = wph + (p ? WH_W8O : WH_W8E);
            f32x4 acc;
            float bias = db3[o0 + lr];
            acc[0] = acc[1] = acc[2] = acc[3] = bias;
            int rb0 = p ? 2 : 1, rb1 = p ? 1 : 0;
            #pragma unroll
            for (int kb = 0; kb < 2; kb++) {
                int rbase = kb ? rb1 : rb0;
                #pragma unroll
                for (int k2 = 0; k2 < 2; k2++) {
                    short8v a = *(const short8v*)&X8[(m0 + lr + rbase) * 72 + k2 * 32 + lk8];
                    short8v w = *(const short8v*)&wb[(o0 + lr) * 136 + kb * 64 + k2 * 32 + lk8];
                    acc = mfma16(a, w, acc);
                }
            }
            #pragma unroll
            for (int r = 0; r < 4; r++) {
                int l = 2 * (m0 + rquad + r) + p;
                Xd[l * 40 + o0 + lr] = f2bfu(acc[r]);   // no relu
            }
        }
    }
    __syncthreads();

    // ---------- P9: MFMA logits GEMM [128l][128v][K=32] -> global ----------
    {
        const unsigned short* owp = wph + WH_OW;
        float* outL = out + OFF_LOG + b * 16384;
        #pragma unroll 4
        for (int q = 0; q < 16; q++) {
            int T = wid * 16 + q;
            int m0 = (T >> 3) * 16, n0 = (T & 7) * 16;
            f32x4 acc;
            float bias = ob[n0 + lr];
            acc[0] = acc[1] = acc[2] = acc[3] = bias;
            short8v a = *(const short8v*)&Xd[(m0 + lr) * 40 + lk8];
            short8v w = *(const short8v*)&owp[(n0 + lr) * 40 + lk8];
            acc = mfma16(a, w, acc);
            #pragma unroll
            for (int r = 0; r < 4; r++)
                outL[(m0 + rquad + r) * 128 + n0 + lr] = acc[r];
        }
    }
}

__global__ void loss_final(const float* __restrict__ part, float* __restrict__ out) {
    __shared__ float red[4];
    const int tid = threadIdx.x;
    float s = 0.f;
    for (int k = tid; k < NBATCH; k += 256) s += part[k];
    #pragma unroll
    for (int off = 32; off; off >>= 1) s += __shfl_down(s, off);
    if ((tid & 63) == 0) red[tid >> 6] = s;
    __syncthreads();
    if (tid == 0) {
        float t = red[0] + red[1] + red[2] + red[3];
        out[OFF_LOSS] = 1.25f * t / 3932160.0f;
    }
}

extern "C" void kernel_launch(void* const* d_in, const int* in_sizes, int n_in,
                              void* d_out, int out_size, void* d_ws, size_t ws_size,
                              hipStream_t stream) {
    const int*   tidx = (const int*)  d_in[0];
    const float* emb  = (const float*)d_in[1];
    const float* w1   = (const float*)d_in[2];
    const float* b1   = (const float*)d_in[3];
    const float* w2   = (const float*)d_in[4];
    const float* b2   = (const float*)d_in[5];
    const float* w3   = (const float*)d_in[6];
    const float* b3   = (const float*)d_in[7];
    const float* cb   = (const float*)d_in[8];
    const float* dw1  = (const float*)d_in[9];
    const float* db1  = (const float*)d_in[10];
    const float* dw2  = (const float*)d_in[11];
    const float* db2  = (const float*)d_in[12];
    const float* dw3  = (const float*)d_in[13];
    const float* db3  = (const float*)d_in[14];
    const float* ow   = (const float*)d_in[15];
    const float* ob   = (const float*)d_in[16];
    float* out = (float*)d_out;
    float* wp  = (float*)d_ws;                                   // f32 packs
    unsigned short* wph = (unsigned short*)((char*)d_ws + 122880); // bf16 packs
    float* part = (float*)((char*)d_ws + WS_LOSS_BYTES);         // [2048]

    prep_weights<<<292, 256, 0, stream>>>(w1, w2, w3, dw1, dw2, dw3, ow, wp, wph);
    vae_fused<<<NBATCH, 256, 0, stream>>>(tidx, emb, b1, b2, b3, cb,
                                          db1, db2, db3, ob, wp, wph,
                                          out, part);
    loss_final<<<1, 256, 0, stream>>>(part, out);
}